// Round 7
// baseline (268.717 us; speedup 1.0000x reference)
//
#include <hip/hip_runtime.h>
#include <math.h>

#define NN   10000
#define EE   200000
#define RR   400000
#define FIN  128
#define FOUT 64
#define NK   10048           // 157*64, K padded for seqT

#define HASH_BITS 20
#define HSIZE (1u << HASH_BITS)
#define HMASK (HSIZE - 1u)
#define ROWCAP 256           // per-row edge slots (Binomial(400K,1e-4): P(>256)~0)

typedef __bf16 bf16x8 __attribute__((ext_vector_type(8)));
typedef __bf16 bf16x4 __attribute__((ext_vector_type(4)));
typedef float  f32x4  __attribute__((ext_vector_type(4)));

// ---- workspace layout (units of 4 bytes) ----
#define O_SUMS   0
#define O_CNTS   (O_SUMS + EE)
#define O_ROWCNT (O_CNTS + EE)             // int[NN]
#define O_HKEY   (O_ROWCNT + NN)
#define O_HPRIO  (O_HKEY + HSIZE)
#define O_SEQT   (O_HPRIO + HSIZE)         // bf16[64][NK] (pad cols must be 0)
#define ZERO_WORDS (O_SEQT + (FOUT * NK) / 2)   // div by 4
#define O_SEQ    ZERO_WORDS                // f32[NN][64]
#define O_NUMP   (O_SEQ + NN * FOUT)       // f32[8][NN][64] partials
#define O_SP     (O_NUMP + 8 * NN * FOUT)  // f32[8][NN]
#define O_PAIRS  (O_SP + 8 * NN)           // uint2[NN][ROWCAP]

// ---------------- wide zero fill ----------------
__global__ __launch_bounds__(256) void k_zero(f32x4* __restrict__ p, int n4) {
    int gid = blockIdx.x * 256 + threadIdx.x;
    if (gid < n4) p[gid] = (f32x4){0.f, 0.f, 0.f, 0.f};
}

// ---------------- seq_fts = x @ W^T  (also emits bf16 transposed copy) ----
__global__ __launch_bounds__(256) void k_seqfts(const float* __restrict__ x,
                                                const float* __restrict__ W,
                                                float* __restrict__ seq,
                                                __bf16* __restrict__ seqT) {
    __shared__ float Wt[FIN][FOUT + 1];
    __shared__ float xs[FIN][16 + 1];
    int t = threadIdx.x;
    for (int e = t; e < FOUT * FIN; e += 256) {
        int c = e >> 7, k = e & 127;
        Wt[k][c] = W[e];
    }
    int row0 = blockIdx.x * 16;
    for (int e = t; e < 16 * FIN; e += 256) {
        int r = e >> 7, k = e & 127;
        int gr = row0 + r;
        xs[k][r] = (gr < NN) ? x[(size_t)gr * FIN + k] : 0.f;
    }
    __syncthreads();
    int col = t & 63;
    int rg  = t >> 6;
    float acc[4] = {0.f, 0.f, 0.f, 0.f};
    for (int k = 0; k < FIN; ++k) {
        float w = Wt[k][col];
        #pragma unroll
        for (int i = 0; i < 4; ++i) acc[i] += w * xs[k][rg * 4 + i];
    }
    #pragma unroll
    for (int i = 0; i < 4; ++i) {
        int gr = row0 + rg * 4 + i;
        if (gr < NN) {
            seq[(size_t)gr * FOUT + col] = acc[i];
            seqT[(size_t)col * NK + gr] = (__bf16)acc[i];
        }
    }
}

// ---------------- helpers ----------------
__device__ __forceinline__ unsigned hash_cell(unsigned cell) {
    return (cell * 2654435761u) >> (32 - HASH_BITS);
}
__device__ __forceinline__ void entry_ij(const int* ep, int e, int& i, int& j, int& k) {
    k = (e < EE) ? e : e - EE;
    int a = ep[2 * k], b = ep[2 * k + 1];
    if (e < EE) { i = a; j = b; } else { i = b; j = a; }
}

// ------- merged: main matmul (partials)  ||  rel segsum  ||  hash build -----
#define BM 64
#define BK 64
#define KSPLIT 8
#define NCHUNK 157
#define CPK ((NCHUNK + KSPLIT - 1) / KSPLIT)   // 20
#define MAINB (NCHUNK * KSPLIT)                // 1256
#define ILV   11                               // 1 main : 10 rel
#define MRB   (ILV * MAINB)                    // 13816 (12560 rel slots)
#define SCATAB ((2 * EE + 255) / 256)          // 1563
#define GRID_MR (MRB + SCATAB)
#define LDAP (BK + 8)

__global__ __launch_bounds__(256) void k_mainrel(const float* __restrict__ adj,
                                                 const __bf16* __restrict__ seqT,
                                                 const float* __restrict__ rel,
                                                 const float* __restrict__ wrel,
                                                 const int* __restrict__ rseg,
                                                 const int* __restrict__ ep,
                                                 float* __restrict__ sums,
                                                 float* __restrict__ cnts,
                                                 unsigned* __restrict__ hkey,
                                                 unsigned* __restrict__ hprio,
                                                 float* __restrict__ Nump,
                                                 float* __restrict__ Sp) {
    __shared__ __bf16 As[2][BM][LDAP];
    __shared__ __bf16 Bs[2][FOUT][LDAP];
    int t   = threadIdx.x;
    int bid = blockIdx.x;

    if (bid >= MRB) {
        // ---- hash-build role (runs in tail; must finish before k_scatB) ----
        int e = (bid - MRB) * 256 + t;
        if (e >= 2 * EE) return;
        int i, j, k;
        entry_ij(ep, e, i, j, k);
        unsigned cell = (unsigned)i * NN + (unsigned)j;
        unsigned keyv = cell + 1u;
        unsigned h = hash_cell(cell);
        while (true) {
            unsigned old = atomicCAS(&hkey[h], 0u, keyv);
            if (old == 0u || old == keyv) break;
            h = (h + 1u) & HMASK;
        }
        atomicMax(&hprio[h], (unsigned)(e + 1));
        return;
    }

    if (bid % ILV) {
        // ---- rel role: 32 rows per block, 32-lane group per row ----
        int relb = bid - bid / ILV - 1;        // [0, 12560)
        int lane = t & 31;
        f32x4 w = *(const f32x4*)(wrel + lane * 4);
        #pragma unroll
        for (int it = 0; it < 4; ++it) {
            int row = relb * 32 + it * 8 + (t >> 5);
            if (row < RR) {
                f32x4 v = *(const f32x4*)(rel + (size_t)row * FIN + lane * 4);
                float s = v.x * w.x + v.y * w.y + v.z * w.z + v.w * w.w;
                #pragma unroll
                for (int off = 16; off >= 1; off >>= 1) s += __shfl_xor(s, off, 64);
                if (lane == 0) {
                    int seg = rseg[row];
                    atomicAdd(&sums[seg], s);
                    atomicAdd(&cnts[seg], 1.0f);
                }
            }
        }
        return;
    }

    // ---- main role ----
    int mi   = bid / ILV;          // [0, 1256)
    int rowc = mi % NCHUNK;
    int ks   = mi / NCHUNK;
    int row0 = rowc * BM;
    int c0   = ks * CPK;
    int c1   = min(NCHUNK, c0 + CPK);
    int w  = t >> 6, l = t & 63;
    int lr = l & 15, lk = l >> 4;
    int sr = t >> 4;               // A-stage row within 16-row strip
    int sk = (t & 15) * 4;         // A-stage col (float4)
    int bc = t >> 3;               // B-stage col 0..31 (+32)
    int bk = (t & 7) * 8;          // B-stage k (bf16x8)

    f32x4 acc[4];
    #pragma unroll
    for (int n = 0; n < 4; ++n) acc[n] = (f32x4){0.f, 0.f, 0.f, 0.f};
    float rs[4] = {0.f, 0.f, 0.f, 0.f};

    f32x4  pva[4];
    bf16x8 pvb0, pvb1;

#define LOADC(CH)                                                              \
    {                                                                          \
        int k0_ = (CH) * BK;                                                   \
        _Pragma("unroll")                                                      \
        for (int e2 = 0; e2 < 4; ++e2) {                                       \
            int gr = row0 + sr + e2 * 16;                                      \
            int gk = k0_ + sk;                                                 \
            bool ok = (gr < NN) && (gk < NN);                                  \
            pva[e2] = ok ? *(const f32x4*)(adj + (size_t)gr * NN + gk)         \
                         : (f32x4){0.f, 0.f, 0.f, 0.f};                        \
        }                                                                      \
        pvb0 = *(const bf16x8*)(seqT + (size_t)bc * NK + k0_ + bk);            \
        pvb1 = *(const bf16x8*)(seqT + (size_t)(bc + 32) * NK + k0_ + bk);     \
    }

    LOADC(c0);
    int p = 0;
    for (int ch = c0; ch < c1; ++ch) {
        // drain prefetch regs into LDS[p] (exp fused for A, row-sums in regs)
        *(bf16x8*)&Bs[p][bc][bk]      = pvb0;
        *(bf16x8*)&Bs[p][bc + 32][bk] = pvb1;
        bool okk = (ch * BK + sk < NN);
        #pragma unroll
        for (int e2 = 0; e2 < 4; ++e2) {
            bool ok = okk && (row0 + sr + e2 * 16 < NN);
            float w0 = ok ? __expf(pva[e2].x + 0.5f) : 0.f;
            float w1 = ok ? __expf(pva[e2].y + 0.5f) : 0.f;
            float w2 = ok ? __expf(pva[e2].z + 0.5f) : 0.f;
            float w3 = ok ? __expf(pva[e2].w + 0.5f) : 0.f;
            bf16x4 bv = { (__bf16)w0, (__bf16)w1, (__bf16)w2, (__bf16)w3 };
            *(bf16x4*)&As[p][sr + e2 * 16][sk] = bv;
            rs[e2] += w0 + w1 + w2 + w3;
        }
        if (ch + 1 < c1) LOADC(ch + 1);        // issue next-chunk loads
        __syncthreads();                        // LDS[p] ready (1 barrier/chunk)
        #pragma unroll
        for (int kss = 0; kss < 2; ++kss) {
            bf16x8 a = *(const bf16x8*)&As[p][w * 16 + lr][kss * 32 + lk * 8];
            #pragma unroll
            for (int n = 0; n < 4; ++n) {
                bf16x8 b = *(const bf16x8*)&Bs[p][n * 16 + lr][kss * 32 + lk * 8];
                acc[n] = __builtin_amdgcn_mfma_f32_16x16x32_bf16(a, b, acc[n], 0, 0, 0);
            }
        }
        p ^= 1;
    }
#undef LOADC

    // row-sum partials: reduce across the 16 lanes sharing a row, plain store
    #pragma unroll
    for (int e = 0; e < 4; ++e) {
        float pp = rs[e];
        pp += __shfl_xor(pp, 1, 64);
        pp += __shfl_xor(pp, 2, 64);
        pp += __shfl_xor(pp, 4, 64);
        pp += __shfl_xor(pp, 8, 64);
        int r = e * 16 + sr;
        if ((t & 15) == 0 && row0 + r < NN)
            Sp[(size_t)ks * NN + row0 + r] = pp;
    }
    // C/D layout: col = lane&15, row = (lane>>4)*4 + reg ; plain stores
    #pragma unroll
    for (int n = 0; n < 4; ++n) {
        #pragma unroll
        for (int r = 0; r < 4; ++r) {
            int grow = row0 + w * 16 + lk * 4 + r;
            if (grow < NN)
                Nump[(size_t)ks * NN * FOUT + (size_t)grow * FOUT + n * 16 + lr]
                    = acc[n][r];
        }
    }
}

// ------- scatB: winner check + dw compute + push (j,dw) into row bucket -----
__global__ __launch_bounds__(256) void k_scatB(const int* __restrict__ ep,
                                               const float* __restrict__ sums,
                                               const float* __restrict__ cnts,
                                               const unsigned* __restrict__ hkey,
                                               const unsigned* __restrict__ hprio,
                                               const float* __restrict__ adj,
                                               int* __restrict__ rowcnt,
                                               uint2* __restrict__ pairs) {
    int e = blockIdx.x * 256 + threadIdx.x;
    if (e >= 2 * EE) return;
    int i, j, k;
    entry_ij(ep, e, i, j, k);
    unsigned cell = (unsigned)i * NN + (unsigned)j;
    unsigned keyv = cell + 1u;
    unsigned h = hash_cell(cell);
    while (hkey[h] != keyv) h = (h + 1u) & HMASK;
    if (hprio[h] == (unsigned)(e + 1)) {   // last-write-wins winner
        float v   = sums[k] / fmaxf(cnts[k], 1.0f);
        float sg  = 1.f / (1.f + __expf(-v));
        float aij = adj[(size_t)i * NN + j];
        float dw  = __expf(aij + sg) - __expf(aij + 0.5f);
        if (dw != 0.f) {
            int pos = atomicAdd(&rowcnt[i], 1);
            if (pos < ROWCAP)
                pairs[(size_t)i * ROWCAP + pos] =
                    make_uint2((unsigned)j, __float_as_uint(dw));
        }
    }
}

// ------- rowupd: one wave per row: sum partials + edge corr + elu -> out ----
__global__ __launch_bounds__(256) void k_rowupd(const float* __restrict__ Nump,
                                                const float* __restrict__ Sp,
                                                const int* __restrict__ rowcnt,
                                                const uint2* __restrict__ pairs,
                                                const float* __restrict__ seq,
                                                const float* __restrict__ bias,
                                                float* __restrict__ out) {
    int t = threadIdx.x;
    int i = blockIdx.x * 4 + (t >> 6);
    if (i >= NN) return;
    int c = t & 63;
    float acc = 0.f, sb = 0.f;
    #pragma unroll
    for (int ks = 0; ks < 8; ++ks) {
        acc += Nump[(size_t)ks * NN * FOUT + (size_t)i * FOUT + c];
        sb  += Sp[(size_t)ks * NN + i];
    }
    int cnt = min(rowcnt[i], ROWCAP);
    float sdw = 0.f;
    const uint2* pr = pairs + (size_t)i * ROWCAP;
    #pragma unroll 4
    for (int e = 0; e < cnt; ++e) {
        uint2 pk = pr[e];                      // wave-uniform broadcast load
        float d  = __uint_as_float(pk.y);
        acc += d * seq[(size_t)pk.x * FOUT + c];
        sdw += d;
    }
    float v = acc / (sb + sdw) + bias[c];
    out[(size_t)i * FOUT + c] = (v > 0.f) ? v : expm1f(v);
}

extern "C" void kernel_launch(void* const* d_in, const int* in_sizes, int n_in,
                              void* d_out, int out_size, void* d_ws, size_t ws_size,
                              hipStream_t stream) {
    const float* x    = (const float*)d_in[0];
    const float* rel  = (const float*)d_in[1];
    const float* adj  = (const float*)d_in[2];
    const int*   ep   = (const int*)d_in[3];
    const int*   rseg = (const int*)d_in[4];
    const float* W    = (const float*)d_in[5];
    const float* wrel = (const float*)d_in[6];
    const float* bias = (const float*)d_in[7];
    float* out = (float*)d_out;

    float* ws = (float*)d_ws;
    float*    sums   = ws + O_SUMS;
    float*    cnts   = ws + O_CNTS;
    int*      rowcnt = (int*)(ws + O_ROWCNT);
    unsigned* hkey   = (unsigned*)(ws + O_HKEY);
    unsigned* hprio  = (unsigned*)(ws + O_HPRIO);
    __bf16*   seqT   = (__bf16*)(ws + O_SEQT);
    float*    seq    = ws + O_SEQ;
    float*    Nump   = ws + O_NUMP;
    float*    Sp     = ws + O_SP;
    uint2*    pairs  = (uint2*)(ws + O_PAIRS);

    int n4 = ZERO_WORDS / 4;
    k_zero<<<(n4 + 255) / 256, 256, 0, stream>>>((f32x4*)d_ws, n4);
    k_seqfts<<<NN / 16, 256, 0, stream>>>(x, W, seq, seqT);
    k_mainrel<<<GRID_MR, 256, 0, stream>>>(adj, seqT, rel, wrel, rseg, ep,
                                           sums, cnts, hkey, hprio, Nump, Sp);
    k_scatB<<<SCATAB, 256, 0, stream>>>(ep, sums, cnts, hkey, hprio, adj,
                                        rowcnt, pairs);
    k_rowupd<<<(NN + 3) / 4, 256, 0, stream>>>(Nump, Sp, rowcnt, pairs,
                                               seq, bias, out);
}